// Round 2
// 8670.575 us; speedup vs baseline: 1.4560x; 1.4560x over previous
//
#include <hip/hip_runtime.h>
#include <stdint.h>

typedef _Float16 f16;
typedef _Float16 f16x8 __attribute__((ext_vector_type(8)));
typedef float f32x4 __attribute__((ext_vector_type(4)));

#define LN_EPS 1e-5f

// ---------------- chunk barrier (proven pattern) ----------------
__device__ __forceinline__ void bar_sync(uint32_t* cnt, uint32_t* gen,
                                         uint32_t n, uint32_t* mygen) {
  __syncthreads();
  if (threadIdx.x == 0) {
    uint32_t g = *mygen;
    uint32_t t = __hip_atomic_fetch_add(cnt, 1u, __ATOMIC_ACQ_REL,
                                        __HIP_MEMORY_SCOPE_AGENT);
    if (t == n - 1u) {
      __hip_atomic_store(cnt, 0u, __ATOMIC_RELAXED, __HIP_MEMORY_SCOPE_AGENT);
      __hip_atomic_store(gen, g + 1u, __ATOMIC_RELEASE, __HIP_MEMORY_SCOPE_AGENT);
    } else {
      while (__hip_atomic_load(gen, __ATOMIC_ACQUIRE,
                               __HIP_MEMORY_SCOPE_AGENT) < g + 1u) {
        __builtin_amdgcn_s_sleep(2);
      }
    }
    *mygen = g + 1u;
  }
  __syncthreads();
}

// ---------------- fused 2-layer pipelined scan ----------------
// 96 WGs x 512 threads. chunk = blk&7 (XCD-local with round-robin dispatch),
// g = blk>>3 (0..11). chunks 0..3 = layer0 rows 16c, chunks 4..7 = layer1.
// Per wave: 16 output cols; weights resident in VGPRs (L0: 64, L1: 128).
// Per step: [L1: spin on L0 progress + stage h0(t)->LDS] -> phase A MFMA ->
// store pre (double-buffered) -> ONE chunk barrier -> phase B (LN/gates,
// redundant in every WG, h written straight into own LDS A-tile).
// pre row layout [2048]: [0..1023]=rz sum, [1024..1535]=u_h part,
// [1536..2047]=x_h part (L1 only; L0 reads x_h from X0).
__global__ __launch_bounds__(512, 2) void scan_fused(
    const f16* __restrict__ X0,      // [512][64][1536] (bias0 folded)
    const f16* __restrict__ W1,      // [1536][512] = [w_rz1; w_h1]
    const f16* __restrict__ U0,      // [1536][512] = [u_rz0; u_h0]
    const f16* __restrict__ U1,      // [1536][512] = [u_rz1; u_h1]
    const float* __restrict__ bias1, // [1536]
    const float* __restrict__ g_rz0, const float* __restrict__ b_rz0,
    const float* __restrict__ g_h0,  const float* __restrict__ b_h0,
    const float* __restrict__ g_rz1, const float* __restrict__ b_rz1,
    const float* __restrict__ g_h1,  const float* __restrict__ b_h1,
    f16* __restrict__ h_all0,        // [512][64][512]
    f16* __restrict__ h_all1,        // [512][64][512]
    float* __restrict__ h32_0, float* __restrict__ h32_1,
    float* __restrict__ pre,         // [2][128][2048] f32
    uint32_t* __restrict__ bars)     // [0..1023] chunk bars, [1024..] progress
{
  const int blk   = blockIdx.x;
  const int chunk = blk & 7;
  const int g     = blk >> 3;          // 0..11
  const int layer = chunk >> 2;        // 0 | 1
  const int rows0 = (chunk & 3) * 16;
  const int tid  = threadIdx.x;
  const int wid  = tid >> 6;           // 0..7
  const int lane = tid & 63;
  const int quad = lane >> 4;
  const int l16  = lane & 15;
  const int col  = g * 128 + wid * 16 + l16;   // this lane's output col
  const bool rz_cols = (g * 128 + wid * 16) < 1024;

  __shared__ f16 Ash[16][1048];        // [h0|h1] tile; stride 1048h = 2-way banks
  __shared__ float lnrg[1024], lnrb[1024], lnhg[512], lnhb[512];

  {
    const float* srg = layer ? g_rz1 : g_rz0;
    const float* srb = layer ? b_rz1 : b_rz0;
    const float* shg = layer ? g_h1  : g_h0;
    const float* shb = layer ? b_h1  : b_h0;
    for (int i = tid; i < 1024; i += 512) { lnrg[i] = srg[i]; lnrb[i] = srb[i]; }
    if (tid < 512) { lnhg[tid] = shg[tid]; lnhb[tid] = shb[tid]; }
    f16* az = &Ash[0][0];
    for (int i = tid; i < 16 * 1048; i += 512) az[i] = (f16)0.f;
  }

  // resident weight fragments
  f16x8 ufw[16], ufu[16];
  if (layer == 0) {
#pragma unroll
    for (int kk = 0; kk < 16; ++kk)
      ufu[kk] = *(const f16x8*)(U0 + (size_t)col * 512 + kk * 32 + quad * 8);
  } else {
#pragma unroll
    for (int kk = 0; kk < 16; ++kk) {
      ufw[kk] = *(const f16x8*)(W1 + (size_t)col * 512 + kk * 32 + quad * 8);
      ufu[kk] = *(const f16x8*)(U1 + (size_t)col * 512 + kk * 32 + quad * 8);
    }
  }
  const float bval = layer ? bias1[col] : 0.f;

  uint32_t* cnt  = bars + (size_t)chunk * 128;
  uint32_t* gen  = cnt + 64;
  uint32_t* prog = bars + 1024 + (size_t)(chunk & 3) * 64;
  uint32_t mygen = 0;

  float hreg[2][8];                    // fp32 h master, rows 2*wid, 2*wid+1
#pragma unroll
  for (int rr = 0; rr < 2; ++rr)
#pragma unroll
    for (int i = 0; i < 8; ++i) hreg[rr][i] = 0.f;

  const size_t prerow0 = (size_t)layer * 64 + rows0;
  f16* h_out = layer ? h_all1 : h_all0;

  for (int t = 0; t < 512; ++t) {
    __syncthreads();                    // phase-B(t-1) LDS h-writes visible
    if (layer == 0) {
      if (g == 0 && tid == 0 && t > 0)
        __hip_atomic_store(prog, (uint32_t)t, __ATOMIC_RELEASE,
                           __HIP_MEMORY_SCOPE_AGENT);
    } else {
      if (tid == 0) {
        while (__hip_atomic_load(prog, __ATOMIC_ACQUIRE,
                                 __HIP_MEMORY_SCOPE_AGENT) < (uint32_t)(t + 1)) {
          __builtin_amdgcn_s_sleep(2);
        }
      }
      __syncthreads();
      {  // stage h0(t) -> Ash[:, 0..511]
        const int r  = tid >> 5;
        const int k0 = (tid & 31) * 16;
        const f16* src = h_all0 + ((size_t)t * 64 + rows0 + r) * 512 + k0;
        *(f16x8*)&Ash[r][k0]     = *(const f16x8*)src;
        *(f16x8*)&Ash[r][k0 + 8] = *(const f16x8*)(src + 8);
      }
      __syncthreads();
    }

    // ---- phase A ----
    f32x4 accw, accu;
    accu = (f32x4){0.f, 0.f, 0.f, 0.f};
    if (layer == 0) {
      if (rz_cols) {
        const size_t xb = ((size_t)t * 64 + rows0 + quad * 4) * 1536 + col;
#pragma unroll
        for (int rr = 0; rr < 4; ++rr) accw[rr] = (float)X0[xb + (size_t)rr * 1536];
      } else {
        accw = (f32x4){0.f, 0.f, 0.f, 0.f};
      }
#pragma unroll
      for (int kk = 0; kk < 8; ++kk) {
        f16x8 af = *(const f16x8*)&Ash[l16][kk * 32 + quad * 8];
        accw = __builtin_amdgcn_mfma_f32_16x16x32_f16(af, ufu[kk], accw, 0, 0, 0);
      }
#pragma unroll
      for (int kk = 8; kk < 16; ++kk) {
        f16x8 af = *(const f16x8*)&Ash[l16][kk * 32 + quad * 8];
        accu = __builtin_amdgcn_mfma_f32_16x16x32_f16(af, ufu[kk], accu, 0, 0, 0);
      }
    } else {
      accw = (f32x4){bval, bval, bval, bval};
#pragma unroll
      for (int kk = 0; kk < 16; ++kk) {
        f16x8 af = *(const f16x8*)&Ash[l16][kk * 32 + quad * 8];
        accw = __builtin_amdgcn_mfma_f32_16x16x32_f16(af, ufw[kk], accw, 0, 0, 0);
      }
#pragma unroll
      for (int kk = 0; kk < 16; ++kk) {
        f16x8 af = *(const f16x8*)&Ash[l16][512 + kk * 32 + quad * 8];
        accu = __builtin_amdgcn_mfma_f32_16x16x32_f16(af, ufu[kk], accu, 0, 0, 0);
      }
    }
    {
      const int buf = t & 1;
      float* prow0 = pre + ((size_t)buf * 128 + prerow0 + quad * 4) * 2048;
      if (layer == 0 || rz_cols) {
#pragma unroll
        for (int rr = 0; rr < 4; ++rr)
          prow0[(size_t)rr * 2048 + col] = accw[rr] + accu[rr];
      } else {
#pragma unroll
        for (int rr = 0; rr < 4; ++rr) {
          prow0[(size_t)rr * 2048 + col]       = accu[rr];   // u_h part
          prow0[(size_t)rr * 2048 + col + 512] = accw[rr];   // x_h part (+bias)
        }
      }
    }

    bar_sync(cnt, gen, 12, &mygen);

    // ---- phase B: redundant in every WG, 2 rows per wave ----
    {
      const int buf = t & 1;
#pragma unroll
      for (int rr = 0; rr < 2; ++rr) {
        const int r    = wid * 2 + rr;
        const int brow = rows0 + r;
        const float* prow =
            pre + ((size_t)buf * 128 + (size_t)layer * 64 + brow) * 2048;
        float v[16];
#pragma unroll
        for (int i = 0; i < 16; ++i) v[i] = prow[i * 64 + lane];
        float s1 = 0.f, s2 = 0.f;
#pragma unroll
        for (int i = 0; i < 16; ++i) { s1 += v[i]; s2 += v[i] * v[i]; }
#pragma unroll
        for (int off = 1; off < 64; off <<= 1) {
          s1 += __shfl_xor(s1, off); s2 += __shfl_xor(s2, off);
        }
        float m    = s1 * (1.f / 1024.f);
        float var  = s2 * (1.f / 1024.f) - m * m;
        float rstd = rsqrtf(var + LN_EPS);
        float rg[8], zg[8];
#pragma unroll
        for (int i = 0; i < 16; ++i) {
          int n = i * 64 + lane;
          float a = (v[i] - m) * rstd * lnrg[n] + lnrb[n];
          float s = 1.f / (1.f + __expf(-a));
          if (i < 8) rg[i] = s; else zg[i - 8] = s;
        }
        float ht[8];
        float u1 = 0.f, u2 = 0.f;
#pragma unroll
        for (int i = 0; i < 8; ++i) {
          int n  = i * 64 + lane;
          float hu = prow[1024 + n];
          float xh = layer ? prow[1536 + n]
                           : (float)X0[((size_t)t * 64 + brow) * 1536 + 1024 + n];
          float hv = xh + rg[i] * hu;
          ht[i] = hv; u1 += hv; u2 += hv * hv;
        }
#pragma unroll
        for (int off = 1; off < 64; off <<= 1) {
          u1 += __shfl_xor(u1, off); u2 += __shfl_xor(u2, off);
        }
        float m2    = u1 * (1.f / 512.f);
        float var2  = u2 * (1.f / 512.f) - m2 * m2;
        float rstd2 = rsqrtf(var2 + LN_EPS);
#pragma unroll
        for (int i = 0; i < 8; ++i) {
          int n = i * 64 + lane;
          float a  = (ht[i] - m2) * rstd2 * lnhg[n] + lnhb[n];
          float th = tanhf(a);
          float hn = (1.f - zg[i]) * hreg[rr][i] + zg[i] * th;
          hreg[rr][i] = hn;
          Ash[r][(layer ? 512 : 0) + n] = (f16)hn;
          if (g == 0) h_out[((size_t)t * 64 + brow) * 512 + n] = (f16)hn;
        }
      }
    }
  }

  __syncthreads();
  if (layer == 0 && g == 0 && tid == 0)
    __hip_atomic_store(prog, 512u, __ATOMIC_RELEASE, __HIP_MEMORY_SCOPE_AGENT);
  if (g == 0) {
    float* hdst = layer ? h32_1 : h32_0;
#pragma unroll
    for (int rr = 0; rr < 2; ++rr) {
      const int brow = rows0 + wid * 2 + rr;
#pragma unroll
      for (int i = 0; i < 8; ++i)
        hdst[(size_t)brow * 512 + i * 64 + lane] = hreg[rr][i];
    }
  }
}

// ---------------- generic K=512 fp16 GEMM: C = A @ W^T + bias ----------------
__global__ void gemm_k512(const f16* __restrict__ A, const f16* __restrict__ W,
                          const float* __restrict__ bias, void* __restrict__ out,
                          int N, int mode)
{
  __shared__ f16 As[128][56];
  __shared__ f16 Bs[128][56];
  const int tid = threadIdx.x;
  const int wid = tid >> 6, lane = tid & 63, quad = lane >> 4, l16 = lane & 15;
  const int wm = wid & 1, wn = wid >> 1;
  const int rb = blockIdx.y * 128, cb = blockIdx.x * 128;
  f32x4 acc[4][4];
#pragma unroll
  for (int i = 0; i < 4; ++i)
#pragma unroll
    for (int j = 0; j < 4; ++j) acc[i][j] = (f32x4){0.f, 0.f, 0.f, 0.f};
  const int srow = tid >> 1;
  const int skh  = (tid & 1) * 16;
  for (int kk = 0; kk < 16; ++kk) {
    __syncthreads();
    {
      const f16* a = A + (size_t)(rb + srow) * 512 + kk * 32 + skh;
      *(f16x8*)&As[srow][skh]     = *(const f16x8*)(a);
      *(f16x8*)&As[srow][skh + 8] = *(const f16x8*)(a + 8);
      const f16* b = W + (size_t)(cb + srow) * 512 + kk * 32 + skh;
      *(f16x8*)&Bs[srow][skh]     = *(const f16x8*)(b);
      *(f16x8*)&Bs[srow][skh + 8] = *(const f16x8*)(b + 8);
    }
    __syncthreads();
    f16x8 af[4], bf[4];
#pragma unroll
    for (int mt = 0; mt < 4; ++mt) af[mt] = *(const f16x8*)&As[wm * 64 + mt * 16 + l16][quad * 8];
#pragma unroll
    for (int nt = 0; nt < 4; ++nt) bf[nt] = *(const f16x8*)&Bs[wn * 64 + nt * 16 + l16][quad * 8];
#pragma unroll
    for (int mt = 0; mt < 4; ++mt)
#pragma unroll
      for (int nt = 0; nt < 4; ++nt)
        acc[mt][nt] = __builtin_amdgcn_mfma_f32_16x16x32_f16(af[mt], bf[nt], acc[mt][nt], 0, 0, 0);
  }
#pragma unroll
  for (int mt = 0; mt < 4; ++mt) {
#pragma unroll
    for (int nt = 0; nt < 4; ++nt) {
#pragma unroll
      for (int rr = 0; rr < 4; ++rr) {
        int grow = rb + wm * 64 + mt * 16 + quad * 4 + rr;
        int gcol = cb + wn * 64 + nt * 16 + l16;
        float vv = acc[mt][nt][rr] + bias[gcol];
        if (mode == 0) {
          ((f16*)out)[(size_t)grow * N + gcol] = (f16)vv;
        } else {
          int b = grow & 63, tt = grow >> 6;
          ((float*)out)[((size_t)b * 512 + tt) * 512 + gcol] = vv;
        }
      }
    }
  }
}

// ---------------- prep: fp16 conversion, transposes, zero-init ----------------
__global__ void prep_kernel(
    const float* __restrict__ x, const float* __restrict__ fc_w,
    const float* __restrict__ w_rz0, const float* __restrict__ b_rz0,
    const float* __restrict__ u_rz0, const float* __restrict__ w_h0,
    const float* __restrict__ b_h0,  const float* __restrict__ u_h0,
    const float* __restrict__ w_rz1, const float* __restrict__ b_rz1,
    const float* __restrict__ u_rz1, const float* __restrict__ w_h1,
    const float* __restrict__ b_h1,  const float* __restrict__ u_h1,
    f16* x16, f16* wcat0, f16* ucat0, f16* wcat1, f16* ucat1, f16* fcw16,
    float* bias0, float* bias1, float* h32_0, float* h32_1, uint32_t* bars)
{
  const int stride = gridDim.x * blockDim.x;
  const int gid = blockIdx.x * blockDim.x + threadIdx.x;
  for (int i = gid; i < 16777216; i += stride) {
    int k = i & 511, b = (i >> 9) & 63, t = i >> 15;
    x16[i] = (f16)x[(((size_t)b << 9) + t) * 512 + k];
  }
  for (int i = gid; i < 786432; i += stride) {
    int n = i >> 9, k = i & 511;
    float a0 = (n < 1024) ? w_rz0[(size_t)n * 512 + k] : w_h0[(size_t)(n - 1024) * 512 + k];
    float c0 = (n < 1024) ? u_rz0[(size_t)n * 512 + k] : u_h0[(size_t)(n - 1024) * 512 + k];
    float a1 = (n < 1024) ? w_rz1[(size_t)n * 512 + k] : w_h1[(size_t)(n - 1024) * 512 + k];
    float c1 = (n < 1024) ? u_rz1[(size_t)n * 512 + k] : u_h1[(size_t)(n - 1024) * 512 + k];
    wcat0[i] = (f16)a0; ucat0[i] = (f16)c0; wcat1[i] = (f16)a1; ucat1[i] = (f16)c1;
  }
  for (int i = gid; i < 262144; i += stride) fcw16[i] = (f16)fc_w[i];
  for (int i = gid; i < 1536; i += stride) {
    bias0[i] = (i < 1024) ? b_rz0[i] : b_h0[i - 1024];
    bias1[i] = (i < 1024) ? b_rz1[i] : b_h1[i - 1024];
  }
  for (int i = gid; i < 32768; i += stride) { h32_0[i] = 0.f; h32_1[i] = 0.f; }
  for (int i = gid; i < 2048; i += stride) bars[i] = 0u;
}

// ---------------- tail: hidden = stack([h0, h1]) ----------------
__global__ void tail_kernel(const float* __restrict__ h32_0,
                            const float* __restrict__ h32_1,
                            float* __restrict__ out)
{
  int i = blockIdx.x * blockDim.x + threadIdx.x;
  if (i < 32768)      out[16777216 + i] = h32_0[i];
  else if (i < 65536) out[16777216 + i] = h32_1[i - 32768];
}

extern "C" void kernel_launch(void* const* d_in, const int* in_sizes, int n_in,
                              void* d_out, int out_size, void* d_ws, size_t ws_size,
                              hipStream_t stream)
{
  const float* x      = (const float*)d_in[0];
  const float* fc_w   = (const float*)d_in[1];
  const float* fc_b   = (const float*)d_in[2];
  const float* l0_w_rz = (const float*)d_in[3];
  const float* l0_b_rz = (const float*)d_in[4];
  const float* l0_u_rz = (const float*)d_in[5];
  const float* l0_w_h  = (const float*)d_in[6];
  const float* l0_b_h  = (const float*)d_in[7];
  const float* l0_u_h  = (const float*)d_in[8];
  const float* l0_g_rz = (const float*)d_in[9];
  const float* l0_be_rz= (const float*)d_in[10];
  const float* l0_g_h  = (const float*)d_in[11];
  const float* l0_be_h = (const float*)d_in[12];
  const float* l1_w_rz = (const float*)d_in[13];
  const float* l1_b_rz = (const float*)d_in[14];
  const float* l1_u_rz = (const float*)d_in[15];
  const float* l1_w_h  = (const float*)d_in[16];
  const float* l1_b_h  = (const float*)d_in[17];
  const float* l1_u_h  = (const float*)d_in[18];
  const float* l1_g_rz = (const float*)d_in[19];
  const float* l1_be_rz= (const float*)d_in[20];
  const float* l1_g_h  = (const float*)d_in[21];
  const float* l1_be_h = (const float*)d_in[22];

  char* ws = (char*)d_ws;
  size_t off = 0;
  auto alloc = [&](size_t bytes) {
    size_t o = off; off += (bytes + 255) & ~(size_t)255; return o;
  };
  f16*   X      = (f16*)  (ws + alloc((size_t)512 * 64 * 1536 * 2)); // X0
  f16*   x16    = (f16*)  (ws + alloc((size_t)512 * 64 * 512 * 2));
  f16*   h_all0 = (f16*)  (ws + alloc((size_t)512 * 64 * 512 * 2));
  f16*   h_all1 = (f16*)  (ws + alloc((size_t)512 * 64 * 512 * 2));
  f16*   wcat0  = (f16*)  (ws + alloc((size_t)1536 * 512 * 2));
  f16*   ucat0  = (f16*)  (ws + alloc((size_t)1536 * 512 * 2));
  f16*   wcat1  = (f16*)  (ws + alloc((size_t)1536 * 512 * 2));
  f16*   ucat1  = (f16*)  (ws + alloc((size_t)1536 * 512 * 2));
  f16*   fcw16  = (f16*)  (ws + alloc((size_t)512 * 512 * 2));
  float* bias0  = (float*)(ws + alloc((size_t)1536 * 4));
  float* bias1  = (float*)(ws + alloc((size_t)1536 * 4));
  float* h32_0  = (float*)(ws + alloc((size_t)64 * 512 * 4));
  float* h32_1  = (float*)(ws + alloc((size_t)64 * 512 * 4));
  float* pre    = (float*)(ws + alloc((size_t)2 * 128 * 2048 * 4));
  uint32_t* bars= (uint32_t*)(ws + alloc((size_t)2048 * 4));

  prep_kernel<<<dim3(2048), dim3(256), 0, stream>>>(
      x, fc_w, l0_w_rz, l0_b_rz, l0_u_rz, l0_w_h, l0_b_h, l0_u_h,
      l1_w_rz, l1_b_rz, l1_u_rz, l1_w_h, l1_b_h, l1_u_h,
      x16, wcat0, ucat0, wcat1, ucat1, fcw16, bias0, bias1,
      h32_0, h32_1, bars);

  // X0 = x @ [w_rz0; w_h0]^T + bias0
  gemm_k512<<<dim3(12, 256), dim3(256), 0, stream>>>(x16, wcat0, bias0, X, 1536, 0);

  // fused, pipelined 2-layer scan
  scan_fused<<<dim3(96), dim3(512), 0, stream>>>(
      X, wcat1, ucat0, ucat1, bias1,
      l0_g_rz, l0_be_rz, l0_g_h, l0_be_h,
      l1_g_rz, l1_be_rz, l1_g_h, l1_be_h,
      h_all0, h_all1, h32_0, h32_1, pre, bars);

  // logits = h1_all @ fc_w^T + fc_b  (B-major into d_out)
  gemm_k512<<<dim3(4, 256), dim3(256), 0, stream>>>(h_all1, fcw16, fc_b, d_out, 512, 1);
  // hidden states
  tail_kernel<<<dim3(256), dim3(256), 0, stream>>>(h32_0, h32_1, (float*)d_out);
}

// Round 3
// 6695.484 us; speedup vs baseline: 1.8855x; 1.2950x over previous
//
#include <hip/hip_runtime.h>
#include <stdint.h>

typedef _Float16 f16;
typedef _Float16 f16x8 __attribute__((ext_vector_type(8)));
typedef float f32x4 __attribute__((ext_vector_type(4)));

#define LN_EPS 1e-5f

// Relaxed agent-scope accesses: compile to sc0/sc1 coherent-point load/store,
// NO cache-maintenance ops (no wbl2 / no invalidate). Ordering is done
// manually with s_waitcnt vmcnt(0) + __syncthreads before signaling.
#define AT_LD(p)   __hip_atomic_load((p), __ATOMIC_RELAXED, __HIP_MEMORY_SCOPE_AGENT)
#define AT_ST(p,v) __hip_atomic_store((p), (v), __ATOMIC_RELAXED, __HIP_MEMORY_SCOPE_AGENT)
#define VM_DRAIN() asm volatile("s_waitcnt vmcnt(0)" ::: "memory")

// ---------------- chunk barrier: monotonic counters, fully relaxed ----------
// Callers must have VM_DRAIN'd their exchange stores before arriving (done at
// entry). Data freshness for readers comes from sc-flagged AT_LD on the data.
__device__ __forceinline__ void bar_sync(uint32_t* cnt, uint32_t* gen,
                                         uint32_t n, uint32_t* epoch) {
  VM_DRAIN();
  __syncthreads();
  if (threadIdx.x == 0) {
    uint32_t e = *epoch + 1u; *epoch = e;
    uint32_t t = __hip_atomic_fetch_add(cnt, 1u, __ATOMIC_RELAXED,
                                        __HIP_MEMORY_SCOPE_AGENT);
    if (t == e * n - 1u) {
      AT_ST(gen, e);
    } else {
      while (AT_LD(gen) < e) __builtin_amdgcn_s_sleep(2);
    }
  }
  __syncthreads();
}

__device__ __forceinline__ float fast_tanh(float a) {
  float x = fminf(fmaxf(a, -20.f), 20.f);
  float e = __expf(-2.f * x);
  return (1.f - e) / (1.f + e);
}

// ---------------- fused 2-layer pipelined scan ----------------
// 96 WGs x 512 threads. chunk = blk&7, g = blk>>3 (0..11).
// chunks 0..3 = layer0 rows 16c, chunks 4..7 = layer1 rows 16(c-4).
// Per wave: 16 output cols; weights resident in VGPRs (L0: 64, L1: 128).
// Per step: [L1: spin on L0 progress + stage h0(t)->LDS] -> phase A MFMA
// (X0 added at store, x_h prefetched to regs) -> pre stores (sc-coherent,
// double-buffered) -> ONE chunk barrier -> phase B (LN/gates, redundant in
// every WG, h written straight into own LDS A-tile).
__global__ __launch_bounds__(512, 2) void scan_fused(
    const f16* __restrict__ X0,      // [512][64][1536] (bias0 folded)
    const f16* __restrict__ W1,      // [1536][512] = [w_rz1; w_h1]
    const f16* __restrict__ U0,      // [1536][512] = [u_rz0; u_h0]
    const f16* __restrict__ U1,      // [1536][512] = [u_rz1; u_h1]
    const float* __restrict__ bias1, // [1536]
    const float* __restrict__ g_rz0, const float* __restrict__ b_rz0,
    const float* __restrict__ g_h0,  const float* __restrict__ b_h0,
    const float* __restrict__ g_rz1, const float* __restrict__ b_rz1,
    const float* __restrict__ g_h1,  const float* __restrict__ b_h1,
    f16* __restrict__ h_all0,        // [512][64][512]
    f16* __restrict__ h_all1,        // [512][64][512]
    float* __restrict__ h32_0, float* __restrict__ h32_1,
    float* __restrict__ pre,         // [2][128][2048] f32
    uint32_t* __restrict__ bars)     // [0..1023] chunk bars, [1024..] progress
{
  const int blk   = blockIdx.x;
  const int chunk = blk & 7;
  const int g     = blk >> 3;          // 0..11
  const int layer = chunk >> 2;        // 0 | 1
  const int rows0 = (chunk & 3) * 16;
  const int tid  = threadIdx.x;
  const int wid  = tid >> 6;           // 0..7
  const int lane = tid & 63;
  const int quad = lane >> 4;
  const int l16  = lane & 15;
  const int col  = g * 128 + wid * 16 + l16;   // this lane's output col
  const bool rz_cols = (g * 128 + wid * 16) < 1024;

  __shared__ f16 Ash[16][1048];        // [h0|h1] tile
  __shared__ float lnrg[1024], lnrb[1024], lnhg[512], lnhb[512];

  {
    const float* srg = layer ? g_rz1 : g_rz0;
    const float* srb = layer ? b_rz1 : b_rz0;
    const float* shg = layer ? g_h1  : g_h0;
    const float* shb = layer ? b_h1  : b_h0;
    for (int i = tid; i < 1024; i += 512) { lnrg[i] = srg[i]; lnrb[i] = srb[i]; }
    if (tid < 512) { lnhg[tid] = shg[tid]; lnhb[tid] = shb[tid]; }
    f16* az = &Ash[0][0];
    for (int i = tid; i < 16 * 1048; i += 512) az[i] = (f16)0.f;
  }

  // resident weight fragments
  f16x8 ufw[16], ufu[16];
  if (layer == 0) {
#pragma unroll
    for (int kk = 0; kk < 16; ++kk)
      ufu[kk] = *(const f16x8*)(U0 + (size_t)col * 512 + kk * 32 + quad * 8);
  } else {
#pragma unroll
    for (int kk = 0; kk < 16; ++kk) {
      ufw[kk] = *(const f16x8*)(W1 + (size_t)col * 512 + kk * 32 + quad * 8);
      ufu[kk] = *(const f16x8*)(U1 + (size_t)col * 512 + kk * 32 + quad * 8);
    }
  }
  const float bval = layer ? bias1[col] : 0.f;

  uint32_t* cnt  = bars + (size_t)chunk * 128;
  uint32_t* gen  = cnt + 64;
  uint32_t* prog = bars + 1024 + (size_t)(chunk & 3) * 64;
  uint32_t epoch = 0;

  float hreg[2][8];                    // fp32 h master, rows 2*wid, 2*wid+1
#pragma unroll
  for (int rr = 0; rr < 2; ++rr)
#pragma unroll
    for (int i = 0; i < 8; ++i) hreg[rr][i] = 0.f;

  const size_t prerow0 = (size_t)layer * 64 + rows0;
  f16* h_out = layer ? h_all1 : h_all0;

  for (int t = 0; t < 512; ++t) {
    VM_DRAIN();                        // own h/pre stores done before signals
    __syncthreads();                   // phase-B(t-1) LDS h-writes visible
    if (layer == 0) {
      if (g == 0 && tid == 0 && t > 0)
        AT_ST(prog, (uint32_t)t);
    } else {
      if (tid == 0) {
        while (AT_LD(prog) < (uint32_t)(t + 1)) __builtin_amdgcn_s_sleep(2);
      }
      __syncthreads();
      {  // stage h0(t) -> Ash[:, 0..511] via coherent 8B loads
        const int r  = tid >> 5;
        const int k0 = (tid & 31) * 16;
        const uint64_t* src =
            (const uint64_t*)(h_all0 + ((size_t)t * 64 + rows0 + r) * 512 + k0);
        uint64_t a0 = AT_LD((uint64_t*)src);
        uint64_t a1 = AT_LD((uint64_t*)src + 1);
        uint64_t a2 = AT_LD((uint64_t*)src + 2);
        uint64_t a3 = AT_LD((uint64_t*)src + 3);
        uint64_t* dst = (uint64_t*)&Ash[r][k0];
        dst[0] = a0; dst[1] = a1; dst[2] = a2; dst[3] = a3;
      }
      __syncthreads();
    }

    // ---- phase A ----
    float xz[4];                       // X0 rz part (added at store)
    f16 xpf[2][8];                     // X0 x_h prefetch for phase B
    if (layer == 0) {
      if (rz_cols) {
        const size_t xb = ((size_t)t * 64 + rows0 + quad * 4) * 1536 + col;
#pragma unroll
        for (int rr = 0; rr < 4; ++rr) xz[rr] = (float)X0[xb + (size_t)rr * 1536];
      }
#pragma unroll
      for (int rr = 0; rr < 2; ++rr) {
        const size_t xh = ((size_t)t * 64 + rows0 + wid * 2 + rr) * 1536 + 1024 + lane;
#pragma unroll
        for (int i = 0; i < 8; ++i) xpf[rr][i] = X0[xh + (size_t)i * 64];
      }
    }

    f32x4 accw = (f32x4){0.f, 0.f, 0.f, 0.f};
    f32x4 accu = (f32x4){0.f, 0.f, 0.f, 0.f};
    if (layer == 0) {
#pragma unroll
      for (int kk = 0; kk < 8; ++kk) {
        f16x8 af = *(const f16x8*)&Ash[l16][kk * 32 + quad * 8];
        accw = __builtin_amdgcn_mfma_f32_16x16x32_f16(af, ufu[kk], accw, 0, 0, 0);
      }
#pragma unroll
      for (int kk = 8; kk < 16; ++kk) {
        f16x8 af = *(const f16x8*)&Ash[l16][kk * 32 + quad * 8];
        accu = __builtin_amdgcn_mfma_f32_16x16x32_f16(af, ufu[kk], accu, 0, 0, 0);
      }
    } else {
      accw = (f32x4){bval, bval, bval, bval};
#pragma unroll
      for (int kk = 0; kk < 16; ++kk) {
        f16x8 af = *(const f16x8*)&Ash[l16][kk * 32 + quad * 8];
        accw = __builtin_amdgcn_mfma_f32_16x16x32_f16(af, ufw[kk], accw, 0, 0, 0);
      }
#pragma unroll
      for (int kk = 0; kk < 16; ++kk) {
        f16x8 af = *(const f16x8*)&Ash[l16][512 + kk * 32 + quad * 8];
        accu = __builtin_amdgcn_mfma_f32_16x16x32_f16(af, ufu[kk], accu, 0, 0, 0);
      }
    }
    {
      const int buf = t & 1;
      float* prow0 = pre + ((size_t)buf * 128 + prerow0 + quad * 4) * 2048;
      if (layer == 0) {
        if (rz_cols) {
#pragma unroll
          for (int rr = 0; rr < 4; ++rr)
            AT_ST(&prow0[(size_t)rr * 2048 + col], accw[rr] + accu[rr] + xz[rr]);
        } else {
#pragma unroll
          for (int rr = 0; rr < 4; ++rr)
            AT_ST(&prow0[(size_t)rr * 2048 + col], accw[rr] + accu[rr]);
        }
      } else if (rz_cols) {
#pragma unroll
        for (int rr = 0; rr < 4; ++rr)
          AT_ST(&prow0[(size_t)rr * 2048 + col], accw[rr] + accu[rr]);
      } else {
#pragma unroll
        for (int rr = 0; rr < 4; ++rr) {
          AT_ST(&prow0[(size_t)rr * 2048 + col],       accu[rr]);  // u_h part
          AT_ST(&prow0[(size_t)rr * 2048 + col + 512], accw[rr]);  // x_h (+bias)
        }
      }
    }

    bar_sync(cnt, gen, 12, &epoch);

    // ---- phase B: redundant in every WG, 2 rows per wave ----
    {
      const int buf = t & 1;
#pragma unroll
      for (int rr = 0; rr < 2; ++rr) {
        const int r    = wid * 2 + rr;
        const int brow = rows0 + r;
        float* prow =
            pre + ((size_t)buf * 128 + (size_t)layer * 64 + brow) * 2048;
        float v[16];
#pragma unroll
        for (int i = 0; i < 16; ++i) v[i] = AT_LD(&prow[i * 64 + lane]);
        float s1 = 0.f, s2 = 0.f;
#pragma unroll
        for (int i = 0; i < 16; ++i) { s1 += v[i]; s2 += v[i] * v[i]; }
#pragma unroll
        for (int off = 1; off < 64; off <<= 1) {
          s1 += __shfl_xor(s1, off); s2 += __shfl_xor(s2, off);
        }
        float m    = s1 * (1.f / 1024.f);
        float var  = s2 * (1.f / 1024.f) - m * m;
        float rstd = rsqrtf(var + LN_EPS);
        float rg[8], zg[8];
#pragma unroll
        for (int i = 0; i < 16; ++i) {
          int n = i * 64 + lane;
          float a = (v[i] - m) * rstd * lnrg[n] + lnrb[n];
          float s = 1.f / (1.f + __expf(-a));
          if (i < 8) rg[i] = s; else zg[i - 8] = s;
        }
        float ht[8];
        float u1 = 0.f, u2 = 0.f;
#pragma unroll
        for (int i = 0; i < 8; ++i) {
          int n  = i * 64 + lane;
          float hu = AT_LD(&prow[1024 + n]);
          float xh = layer ? AT_LD(&prow[1536 + n]) : (float)xpf[rr][i];
          float hv = xh + rg[i] * hu;
          ht[i] = hv; u1 += hv; u2 += hv * hv;
        }
#pragma unroll
        for (int off = 1; off < 64; off <<= 1) {
          u1 += __shfl_xor(u1, off); u2 += __shfl_xor(u2, off);
        }
        float m2    = u1 * (1.f / 512.f);
        float var2  = u2 * (1.f / 512.f) - m2 * m2;
        float rstd2 = rsqrtf(var2 + LN_EPS);
#pragma unroll
        for (int i = 0; i < 8; ++i) {
          int n = i * 64 + lane;
          float a  = (ht[i] - m2) * rstd2 * lnhg[n] + lnhb[n];
          float th = fast_tanh(a);
          float hn = (1.f - zg[i]) * hreg[rr][i] + zg[i] * th;
          hreg[rr][i] = hn;
          Ash[r][(layer ? 512 : 0) + n] = (f16)hn;
          if (g == 0) {
            union { f16 h; uint16_t u; } cv; cv.h = (f16)hn;
            AT_ST((uint16_t*)&h_out[((size_t)t * 64 + brow) * 512 + n], cv.u);
          }
        }
      }
    }
  }

  VM_DRAIN();
  __syncthreads();
  if (layer == 0 && g == 0 && tid == 0)
    AT_ST(prog, 512u);
  if (g == 0) {
    float* hdst = layer ? h32_1 : h32_0;
#pragma unroll
    for (int rr = 0; rr < 2; ++rr) {
      const int brow = rows0 + wid * 2 + rr;
#pragma unroll
      for (int i = 0; i < 8; ++i)
        hdst[(size_t)brow * 512 + i * 64 + lane] = hreg[rr][i];
    }
  }
}

// ---------------- generic K=512 fp16 GEMM: C = A @ W^T + bias ----------------
__global__ void gemm_k512(const f16* __restrict__ A, const f16* __restrict__ W,
                          const float* __restrict__ bias, void* __restrict__ out,
                          int N, int mode)
{
  __shared__ f16 As[128][56];
  __shared__ f16 Bs[128][56];
  const int tid = threadIdx.x;
  const int wid = tid >> 6, lane = tid & 63, quad = lane >> 4, l16 = lane & 15;
  const int wm = wid & 1, wn = wid >> 1;
  const int rb = blockIdx.y * 128, cb = blockIdx.x * 128;
  f32x4 acc[4][4];
#pragma unroll
  for (int i = 0; i < 4; ++i)
#pragma unroll
    for (int j = 0; j < 4; ++j) acc[i][j] = (f32x4){0.f, 0.f, 0.f, 0.f};
  const int srow = tid >> 1;
  const int skh  = (tid & 1) * 16;
  for (int kk = 0; kk < 16; ++kk) {
    __syncthreads();
    {
      const f16* a = A + (size_t)(rb + srow) * 512 + kk * 32 + skh;
      *(f16x8*)&As[srow][skh]     = *(const f16x8*)(a);
      *(f16x8*)&As[srow][skh + 8] = *(const f16x8*)(a + 8);
      const f16* b = W + (size_t)(cb + srow) * 512 + kk * 32 + skh;
      *(f16x8*)&Bs[srow][skh]     = *(const f16x8*)(b);
      *(f16x8*)&Bs[srow][skh + 8] = *(const f16x8*)(b + 8);
    }
    __syncthreads();
    f16x8 af[4], bf[4];
#pragma unroll
    for (int mt = 0; mt < 4; ++mt) af[mt] = *(const f16x8*)&As[wm * 64 + mt * 16 + l16][quad * 8];
#pragma unroll
    for (int nt = 0; nt < 4; ++nt) bf[nt] = *(const f16x8*)&Bs[wn * 64 + nt * 16 + l16][quad * 8];
#pragma unroll
    for (int mt = 0; mt < 4; ++mt)
#pragma unroll
      for (int nt = 0; nt < 4; ++nt)
        acc[mt][nt] = __builtin_amdgcn_mfma_f32_16x16x32_f16(af[mt], bf[nt], acc[mt][nt], 0, 0, 0);
  }
#pragma unroll
  for (int mt = 0; mt < 4; ++mt) {
#pragma unroll
    for (int nt = 0; nt < 4; ++nt) {
#pragma unroll
      for (int rr = 0; rr < 4; ++rr) {
        int grow = rb + wm * 64 + mt * 16 + quad * 4 + rr;
        int gcol = cb + wn * 64 + nt * 16 + l16;
        float vv = acc[mt][nt][rr] + bias[gcol];
        if (mode == 0) {
          ((f16*)out)[(size_t)grow * N + gcol] = (f16)vv;
        } else {
          int b = grow & 63, tt = grow >> 6;
          ((float*)out)[((size_t)b * 512 + tt) * 512 + gcol] = vv;
        }
      }
    }
  }
}

// ---------------- prep: fp16 conversion, transposes, zero-init ----------------
__global__ void prep_kernel(
    const float* __restrict__ x, const float* __restrict__ fc_w,
    const float* __restrict__ w_rz0, const float* __restrict__ b_rz0,
    const float* __restrict__ u_rz0, const float* __restrict__ w_h0,
    const float* __restrict__ b_h0,  const float* __restrict__ u_h0,
    const float* __restrict__ w_rz1, const float* __restrict__ b_rz1,
    const float* __restrict__ u_rz1, const float* __restrict__ w_h1,
    const float* __restrict__ b_h1,  const float* __restrict__ u_h1,
    f16* x16, f16* wcat0, f16* ucat0, f16* wcat1, f16* ucat1, f16* fcw16,
    float* bias0, float* bias1, float* h32_0, float* h32_1, uint32_t* bars)
{
  const int stride = gridDim.x * blockDim.x;
  const int gid = blockIdx.x * blockDim.x + threadIdx.x;
  for (int i = gid; i < 16777216; i += stride) {
    int k = i & 511, b = (i >> 9) & 63, t = i >> 15;
    x16[i] = (f16)x[(((size_t)b << 9) + t) * 512 + k];
  }
  for (int i = gid; i < 786432; i += stride) {
    int n = i >> 9, k = i & 511;
    float a0 = (n < 1024) ? w_rz0[(size_t)n * 512 + k] : w_h0[(size_t)(n - 1024) * 512 + k];
    float c0 = (n < 1024) ? u_rz0[(size_t)n * 512 + k] : u_h0[(size_t)(n - 1024) * 512 + k];
    float a1 = (n < 1024) ? w_rz1[(size_t)n * 512 + k] : w_h1[(size_t)(n - 1024) * 512 + k];
    float c1 = (n < 1024) ? u_rz1[(size_t)n * 512 + k] : u_h1[(size_t)(n - 1024) * 512 + k];
    wcat0[i] = (f16)a0; ucat0[i] = (f16)c0; wcat1[i] = (f16)a1; ucat1[i] = (f16)c1;
  }
  for (int i = gid; i < 262144; i += stride) fcw16[i] = (f16)fc_w[i];
  for (int i = gid; i < 1536; i += stride) {
    bias0[i] = (i < 1024) ? b_rz0[i] : b_h0[i - 1024];
    bias1[i] = (i < 1024) ? b_rz1[i] : b_h1[i - 1024];
  }
  for (int i = gid; i < 32768; i += stride) { h32_0[i] = 0.f; h32_1[i] = 0.f; }
  for (int i = gid; i < 2048; i += stride) bars[i] = 0u;
}

// ---------------- tail: hidden = stack([h0, h1]) ----------------
__global__ void tail_kernel(const float* __restrict__ h32_0,
                            const float* __restrict__ h32_1,
                            float* __restrict__ out)
{
  int i = blockIdx.x * blockDim.x + threadIdx.x;
  if (i < 32768)      out[16777216 + i] = h32_0[i];
  else if (i < 65536) out[16777216 + i] = h32_1[i - 32768];
}

extern "C" void kernel_launch(void* const* d_in, const int* in_sizes, int n_in,
                              void* d_out, int out_size, void* d_ws, size_t ws_size,
                              hipStream_t stream)
{
  const float* x      = (const float*)d_in[0];
  const float* fc_w   = (const float*)d_in[1];
  const float* fc_b   = (const float*)d_in[2];
  const float* l0_w_rz = (const float*)d_in[3];
  const float* l0_b_rz = (const float*)d_in[4];
  const float* l0_u_rz = (const float*)d_in[5];
  const float* l0_w_h  = (const float*)d_in[6];
  const float* l0_b_h  = (const float*)d_in[7];
  const float* l0_u_h  = (const float*)d_in[8];
  const float* l0_g_rz = (const float*)d_in[9];
  const float* l0_be_rz= (const float*)d_in[10];
  const float* l0_g_h  = (const float*)d_in[11];
  const float* l0_be_h = (const float*)d_in[12];
  const float* l1_w_rz = (const float*)d_in[13];
  const float* l1_b_rz = (const float*)d_in[14];
  const float* l1_u_rz = (const float*)d_in[15];
  const float* l1_w_h  = (const float*)d_in[16];
  const float* l1_b_h  = (const float*)d_in[17];
  const float* l1_u_h  = (const float*)d_in[18];
  const float* l1_g_rz = (const float*)d_in[19];
  const float* l1_be_rz= (const float*)d_in[20];
  const float* l1_g_h  = (const float*)d_in[21];
  const float* l1_be_h = (const float*)d_in[22];

  char* ws = (char*)d_ws;
  size_t off = 0;
  auto alloc = [&](size_t bytes) {
    size_t o = off; off += (bytes + 255) & ~(size_t)255; return o;
  };
  f16*   X      = (f16*)  (ws + alloc((size_t)512 * 64 * 1536 * 2)); // X0
  f16*   x16    = (f16*)  (ws + alloc((size_t)512 * 64 * 512 * 2));
  f16*   h_all0 = (f16*)  (ws + alloc((size_t)512 * 64 * 512 * 2));
  f16*   h_all1 = (f16*)  (ws + alloc((size_t)512 * 64 * 512 * 2));
  f16*   wcat0  = (f16*)  (ws + alloc((size_t)1536 * 512 * 2));
  f16*   ucat0  = (f16*)  (ws + alloc((size_t)1536 * 512 * 2));
  f16*   wcat1  = (f16*)  (ws + alloc((size_t)1536 * 512 * 2));
  f16*   ucat1  = (f16*)  (ws + alloc((size_t)1536 * 512 * 2));
  f16*   fcw16  = (f16*)  (ws + alloc((size_t)512 * 512 * 2));
  float* bias0  = (float*)(ws + alloc((size_t)1536 * 4));
  float* bias1  = (float*)(ws + alloc((size_t)1536 * 4));
  float* h32_0  = (float*)(ws + alloc((size_t)64 * 512 * 4));
  float* h32_1  = (float*)(ws + alloc((size_t)64 * 512 * 4));
  float* pre    = (float*)(ws + alloc((size_t)2 * 128 * 2048 * 4));
  uint32_t* bars= (uint32_t*)(ws + alloc((size_t)2048 * 4));

  prep_kernel<<<dim3(2048), dim3(256), 0, stream>>>(
      x, fc_w, l0_w_rz, l0_b_rz, l0_u_rz, l0_w_h, l0_b_h, l0_u_h,
      l1_w_rz, l1_b_rz, l1_u_rz, l1_w_h, l1_b_h, l1_u_h,
      x16, wcat0, ucat0, wcat1, ucat1, fcw16, bias0, bias1,
      h32_0, h32_1, bars);

  // X0 = x @ [w_rz0; w_h0]^T + bias0
  gemm_k512<<<dim3(12, 256), dim3(256), 0, stream>>>(x16, wcat0, bias0, X, 1536, 0);

  // fused, pipelined 2-layer scan
  scan_fused<<<dim3(96), dim3(512), 0, stream>>>(
      X, wcat1, ucat0, ucat1, bias1,
      l0_g_rz, l0_be_rz, l0_g_h, l0_be_h,
      l1_g_rz, l1_be_rz, l1_g_h, l1_be_h,
      h_all0, h_all1, h32_0, h32_1, pre, bars);

  // logits = h1_all @ fc_w^T + fc_b  (B-major into d_out)
  gemm_k512<<<dim3(4, 256), dim3(256), 0, stream>>>(h_all1, fcw16, fc_b, d_out, 512, 1);
  // hidden states
  tail_kernel<<<dim3(256), dim3(256), 0, stream>>>(h32_0, h32_1, (float*)d_out);
}

// Round 6
// 6317.692 us; speedup vs baseline: 1.9982x; 1.0598x over previous
//
#include <hip/hip_runtime.h>
#include <stdint.h>

typedef _Float16 f16;
typedef _Float16 f16x8 __attribute__((ext_vector_type(8)));
typedef float f32x4 __attribute__((ext_vector_type(4)));

#define LN_EPS 1e-5f

// ---- agent-scope (memory-side coherence point) relaxed ops: proven path ----
#define AT_LD(p)   __hip_atomic_load((p), __ATOMIC_RELAXED, __HIP_MEMORY_SCOPE_AGENT)
#define AT_ST(p,v) __hip_atomic_store((p), (v), __ATOMIC_RELAXED, __HIP_MEMORY_SCOPE_AGENT)
#define VM_DRAIN() asm volatile("s_waitcnt vmcnt(0)" ::: "memory")

// ---------------- slot-broadcast chunk barrier (no RMW chain) ---------------
// Each WG stores its epoch to its own slot (64B apart); lanes 0..11 of wave 0
// poll all 12 slots in parallel. Monotonic epochs, relaxed agent atomics.
// Callers' exchange stores are drained (VM_DRAIN + syncthreads) before the
// slot store, so slot>=e implies that WG's data is visible (round-3 proven
// drain->signal pattern).
__device__ __forceinline__ void bar_slot(uint32_t* slots, int g, uint32_t e,
                                         int tid) {
  VM_DRAIN();
  __syncthreads();
  if (tid == 0) AT_ST(&slots[g * 16], e);
  if (tid < 12) {
    while (AT_LD(&slots[tid * 16]) < e) __builtin_amdgcn_s_sleep(1);
  }
  __syncthreads();
}

__device__ __forceinline__ float fast_tanh(float a) {
  float x = fminf(fmaxf(a, -20.f), 20.f);
  float e = __expf(-2.f * x);
  return (1.f - e) / (1.f + e);
}

// ---------------- fused 2-layer pipelined scan ----------------
// 96 WGs x 512 threads. chunk = blk&7, g = blk>>3 (0..11).
// chunks 0..3 = layer0 rows 16c, chunks 4..7 = layer1 rows 16(c-4).
// Per wave: 16 output cols; weights resident in VGPRs (L0: 64, L1: 128).
// Per step: phase A MFMA (L1: U1-half first, then prog-spin + h0 stage, then
// W1-half) -> pre stores -> slot barrier -> [issue X(t+1) prefetch] ->
// phase B (LN/gates, redundant in every WG, h written to own LDS A-tile).
__global__ __launch_bounds__(512, 2) void scan_fused(
    const f16* __restrict__ X0,      // [512][64][1536] (bias0 folded)
    const f16* __restrict__ W1,      // [1536][512] = [w_rz1; w_h1]
    const f16* __restrict__ U0,      // [1536][512] = [u_rz0; u_h0]
    const f16* __restrict__ U1,      // [1536][512] = [u_rz1; u_h1]
    const float* __restrict__ bias1, // [1536]
    const float* __restrict__ g_rz0, const float* __restrict__ b_rz0,
    const float* __restrict__ g_h0,  const float* __restrict__ b_h0,
    const float* __restrict__ g_rz1, const float* __restrict__ b_rz1,
    const float* __restrict__ g_h1,  const float* __restrict__ b_h1,
    f16* __restrict__ h_all0,        // [512][64][512]
    f16* __restrict__ h_all1,        // [512][64][512]
    float* __restrict__ h32_0, float* __restrict__ h32_1,
    float* __restrict__ pre,         // [2][128][2048] f32
    uint32_t* __restrict__ bars)     // chunk c: slots @ c*256 (12 x stride16);
                                     // prog @ 2048+(c&3)*64
{
  const int blk   = blockIdx.x;
  const int chunk = blk & 7;
  const int g     = blk >> 3;          // 0..11
  const int layer = chunk >> 2;        // 0 | 1
  const int rows0 = (chunk & 3) * 16;
  const int tid  = threadIdx.x;
  const int wid  = tid >> 6;           // 0..7
  const int lane = tid & 63;
  const int quad = lane >> 4;
  const int l16  = lane & 15;
  const int col  = g * 128 + wid * 16 + l16;   // this lane's output col
  const bool rz_cols = (g * 128 + wid * 16) < 1024;

  __shared__ f16 Ash[16][1048];        // [h0|h1] tile
  __shared__ float lnrg[1024], lnrb[1024], lnhg[512], lnhb[512];

  {
    const float* srg = layer ? g_rz1 : g_rz0;
    const float* srb = layer ? b_rz1 : b_rz0;
    const float* shg = layer ? g_h1  : g_h0;
    const float* shb = layer ? b_h1  : b_h0;
    for (int i = tid; i < 1024; i += 512) { lnrg[i] = srg[i]; lnrb[i] = srb[i]; }
    if (tid < 512) { lnhg[tid] = shg[tid]; lnhb[tid] = shb[tid]; }
    f16* az = &Ash[0][0];
    for (int i = tid; i < 16 * 1048; i += 512) az[i] = (f16)0.f;
  }

  // resident weight fragments
  f16x8 ufw[16], ufu[16];
  if (layer == 0) {
#pragma unroll
    for (int kk = 0; kk < 16; ++kk)
      ufu[kk] = *(const f16x8*)(U0 + (size_t)col * 512 + kk * 32 + quad * 8);
  } else {
#pragma unroll
    for (int kk = 0; kk < 16; ++kk) {
      ufw[kk] = *(const f16x8*)(W1 + (size_t)col * 512 + kk * 32 + quad * 8);
      ufu[kk] = *(const f16x8*)(U1 + (size_t)col * 512 + kk * 32 + quad * 8);
    }
  }
  const float bval = layer ? bias1[col] : 0.f;

  uint32_t* slots = bars + (size_t)chunk * 256;
  uint32_t* prog  = bars + 2048 + (size_t)(chunk & 3) * 64;

  float hreg[2][8];                    // fp32 h master, rows 2*wid, 2*wid+1
#pragma unroll
  for (int rr = 0; rr < 2; ++rr)
#pragma unroll
    for (int i = 0; i < 8; ++i) hreg[rr][i] = 0.f;

  const size_t prerow0 = (size_t)layer * 64 + rows0;
  f16* h_out = layer ? h_all1 : h_all0;

  // ---- X prefetch (L0 only): t=0 values into current registers ----
  float xzc[4] = {0.f, 0.f, 0.f, 0.f};
  f16 xpfc[2][8];
  if (layer == 0) {
    if (rz_cols) {
      const size_t xb = ((size_t)rows0 + quad * 4) * 1536 + col;
#pragma unroll
      for (int rr = 0; rr < 4; ++rr) xzc[rr] = (float)X0[xb + (size_t)rr * 1536];
    }
#pragma unroll
    for (int rr = 0; rr < 2; ++rr) {
      const size_t xh = ((size_t)rows0 + wid * 2 + rr) * 1536 + 1024 + lane;
#pragma unroll
      for (int i = 0; i < 8; ++i) xpfc[rr][i] = X0[xh + (size_t)i * 64];
    }
  }

  for (int t = 0; t < 512; ++t) {
    VM_DRAIN();                        // own h_all stores (t-1) drained
    __syncthreads();                   // phase-B(t-1) LDS h-writes visible
    if (layer == 0 && g == 0 && tid == 0 && t > 0)
      AT_ST(prog, (uint32_t)t);        // h_all0[t-1] ready

    // ---- phase A ----
    f32x4 accw = (f32x4){0.f, 0.f, 0.f, 0.f};
    f32x4 accu = (f32x4){0.f, 0.f, 0.f, 0.f};
    if (layer == 0) {
#pragma unroll
      for (int kk = 0; kk < 8; ++kk) {
        f16x8 af = *(const f16x8*)&Ash[l16][kk * 32 + quad * 8];
        accw = __builtin_amdgcn_mfma_f32_16x16x32_f16(af, ufu[kk], accw, 0, 0, 0);
      }
#pragma unroll
      for (int kk = 8; kk < 16; ++kk) {
        f16x8 af = *(const f16x8*)&Ash[l16][kk * 32 + quad * 8];
        accu = __builtin_amdgcn_mfma_f32_16x16x32_f16(af, ufu[kk], accu, 0, 0, 0);
      }
    } else {
      accw = (f32x4){bval, bval, bval, bval};
      // U1 half first: h1(t-1) already in Ash[.][512..1023]
#pragma unroll
      for (int kk = 0; kk < 16; ++kk) {
        f16x8 af = *(const f16x8*)&Ash[l16][512 + kk * 32 + quad * 8];
        accu = __builtin_amdgcn_mfma_f32_16x16x32_f16(af, ufu[kk], accu, 0, 0, 0);
      }
      // wait for h0(t) from layer-0 chunk (overlapped with the MFMAs above)
      if (tid == 0) {
        while (AT_LD(prog) < (uint32_t)(t + 1)) __builtin_amdgcn_s_sleep(1);
      }
      __syncthreads();
      {  // stage h0(t) -> Ash[:, 0..511] via coherent 8B loads (cross-XCD)
        const int r  = tid >> 5;
        const int k0 = (tid & 31) * 16;
        const uint64_t* src =
            (const uint64_t*)(h_all0 + ((size_t)t * 64 + rows0 + r) * 512 + k0);
        uint64_t a0 = AT_LD((uint64_t*)src);
        uint64_t a1 = AT_LD((uint64_t*)src + 1);
        uint64_t a2 = AT_LD((uint64_t*)src + 2);
        uint64_t a3 = AT_LD((uint64_t*)src + 3);
        uint64_t* dst = (uint64_t*)&Ash[r][k0];
        dst[0] = a0; dst[1] = a1; dst[2] = a2; dst[3] = a3;
      }
      __syncthreads();
      // W1 half: h0(t)
#pragma unroll
      for (int kk = 0; kk < 16; ++kk) {
        f16x8 af = *(const f16x8*)&Ash[l16][kk * 32 + quad * 8];
        accw = __builtin_amdgcn_mfma_f32_16x16x32_f16(af, ufw[kk], accw, 0, 0, 0);
      }
    }

    // ---- pre stores (double-buffered) ----
    const int buf = t & 1;
    {
      float* prow0 = pre + ((size_t)buf * 128 + prerow0 + quad * 4) * 2048;
      if (layer == 0) {
#pragma unroll
        for (int rr = 0; rr < 4; ++rr)
          AT_ST(&prow0[(size_t)rr * 2048 + col], accw[rr] + accu[rr] + xzc[rr]);
      } else if (rz_cols) {
#pragma unroll
        for (int rr = 0; rr < 4; ++rr)
          AT_ST(&prow0[(size_t)rr * 2048 + col], accw[rr] + accu[rr]);
      } else {
#pragma unroll
        for (int rr = 0; rr < 4; ++rr) {
          AT_ST(&prow0[(size_t)rr * 2048 + col],       accu[rr]);  // u_h part
          AT_ST(&prow0[(size_t)rr * 2048 + col + 512], accw[rr]);  // x_h (+bias)
        }
      }
    }

    bar_slot(slots, g, (uint32_t)(t + 1), tid);

    // ---- X(t+1) prefetch (L0): latency hides under phase-B VALU ----
    float xzn[4] = {0.f, 0.f, 0.f, 0.f};
    f16 xpfn[2][8];
    if (layer == 0) {
      const int tn = (t < 511) ? t + 1 : 511;
      if (rz_cols) {
        const size_t xb = ((size_t)tn * 64 + rows0 + quad * 4) * 1536 + col;
#pragma unroll
        for (int rr = 0; rr < 4; ++rr) xzn[rr] = (float)X0[xb + (size_t)rr * 1536];
      }
#pragma unroll
      for (int rr = 0; rr < 2; ++rr) {
        const size_t xh = ((size_t)tn * 64 + rows0 + wid * 2 + rr) * 1536 + 1024 + lane;
#pragma unroll
        for (int i = 0; i < 8; ++i) xpfn[rr][i] = X0[xh + (size_t)i * 64];
      }
    }

    // ---- phase B: redundant in every WG, 2 rows per wave ----
#pragma unroll
    for (int rr = 0; rr < 2; ++rr) {
      const int r    = wid * 2 + rr;
      const int brow = rows0 + r;
      float* prow =
          pre + ((size_t)buf * 128 + (size_t)layer * 64 + brow) * 2048;
      float v[16], hu[8], xh[8];
#pragma unroll
      for (int i = 0; i < 16; ++i) v[i] = AT_LD(&prow[i * 64 + lane]);
#pragma unroll
      for (int i = 0; i < 8; ++i)  hu[i] = AT_LD(&prow[1024 + i * 64 + lane]);
      if (layer) {
#pragma unroll
        for (int i = 0; i < 8; ++i) xh[i] = AT_LD(&prow[1536 + i * 64 + lane]);
      }
      float s1 = 0.f, s2 = 0.f;
#pragma unroll
      for (int i = 0; i < 16; ++i) { s1 += v[i]; s2 += v[i] * v[i]; }
#pragma unroll
      for (int off = 1; off < 64; off <<= 1) {
        s1 += __shfl_xor(s1, off); s2 += __shfl_xor(s2, off);
      }
      float m    = s1 * (1.f / 1024.f);
      float var  = s2 * (1.f / 1024.f) - m * m;
      float rstd = rsqrtf(var + LN_EPS);
      float rg[8], zg[8];
#pragma unroll
      for (int i = 0; i < 16; ++i) {
        int n = i * 64 + lane;
        float a = (v[i] - m) * rstd * lnrg[n] + lnrb[n];
        float s = 1.f / (1.f + __expf(-a));
        if (i < 8) rg[i] = s; else zg[i - 8] = s;
      }
      float ht[8];
      float u1 = 0.f, u2 = 0.f;
#pragma unroll
      for (int i = 0; i < 8; ++i) {
        float xv = layer ? xh[i] : (float)xpfc[rr][i];
        float hv = xv + rg[i] * hu[i];
        ht[i] = hv; u1 += hv; u2 += hv * hv;
      }
#pragma unroll
      for (int off = 1; off < 64; off <<= 1) {
        u1 += __shfl_xor(u1, off); u2 += __shfl_xor(u2, off);
      }
      float m2    = u1 * (1.f / 512.f);
      float var2  = u2 * (1.f / 512.f) - m2 * m2;
      float rstd2 = rsqrtf(var2 + LN_EPS);
#pragma unroll
      for (int i = 0; i < 8; ++i) {
        int n = i * 64 + lane;
        float a  = (ht[i] - m2) * rstd2 * lnhg[n] + lnhb[n];
        float th = fast_tanh(a);
        float hn = (1.f - zg[i]) * hreg[rr][i] + zg[i] * th;
        hreg[rr][i] = hn;
        Ash[r][(layer ? 512 : 0) + n] = (f16)hn;
        if (g == 0) {
          if (layer) {
            h_out[((size_t)t * 64 + brow) * 512 + n] = (f16)hn;  // plain store
          } else {
            union { f16 h; uint16_t u; } cv; cv.h = (f16)hn;
            AT_ST((uint16_t*)&h_out[((size_t)t * 64 + brow) * 512 + n], cv.u);
          }
        }
      }
    }

    // roll X prefetch registers
    if (layer == 0) {
#pragma unroll
      for (int rr = 0; rr < 4; ++rr) xzc[rr] = xzn[rr];
#pragma unroll
      for (int rr = 0; rr < 2; ++rr)
#pragma unroll
        for (int i = 0; i < 8; ++i) xpfc[rr][i] = xpfn[rr][i];
    }
  }

  VM_DRAIN();
  __syncthreads();
  if (layer == 0 && g == 0 && tid == 0)
    AT_ST(prog, 512u);
  if (g == 0) {
    float* hdst = layer ? h32_1 : h32_0;
#pragma unroll
    for (int rr = 0; rr < 2; ++rr) {
      const int brow = rows0 + wid * 2 + rr;
#pragma unroll
      for (int i = 0; i < 8; ++i)
        hdst[(size_t)brow * 512 + i * 64 + lane] = hreg[rr][i];
    }
  }
}

// ---------------- generic K=512 fp16 GEMM: C = A @ W^T + bias ----------------
__global__ void gemm_k512(const f16* __restrict__ A, const f16* __restrict__ W,
                          const float* __restrict__ bias, void* __restrict__ out,
                          int N, int mode)
{
  __shared__ f16 As[128][56];
  __shared__ f16 Bs[128][56];
  const int tid = threadIdx.x;
  const int wid = tid >> 6, lane = tid & 63, quad = lane >> 4, l16 = lane & 15;
  const int wm = wid & 1, wn = wid >> 1;
  const int rb = blockIdx.y * 128, cb = blockIdx.x * 128;
  f32x4 acc[4][4];
#pragma unroll
  for (int i = 0; i < 4; ++i)
#pragma unroll
    for (int j = 0; j < 4; ++j) acc[i][j] = (f32x4){0.f, 0.f, 0.f, 0.f};
  const int srow = tid >> 1;
  const int skh  = (tid & 1) * 16;
  for (int kk = 0; kk < 16; ++kk) {
    __syncthreads();
    {
      const f16* a = A + (size_t)(rb + srow) * 512 + kk * 32 + skh;
      *(f16x8*)&As[srow][skh]     = *(const f16x8*)(a);
      *(f16x8*)&As[srow][skh + 8] = *(const f16x8*)(a + 8);
      const f16* b = W + (size_t)(cb + srow) * 512 + kk * 32 + skh;
      *(f16x8*)&Bs[srow][skh]     = *(const f16x8*)(b);
      *(f16x8*)&Bs[srow][skh + 8] = *(const f16x8*)(b + 8);
    }
    __syncthreads();
    f16x8 af[4], bf[4];
#pragma unroll
    for (int mt = 0; mt < 4; ++mt) af[mt] = *(const f16x8*)&As[wm * 64 + mt * 16 + l16][quad * 8];
#pragma unroll
    for (int nt = 0; nt < 4; ++nt) bf[nt] = *(const f16x8*)&Bs[wn * 64 + nt * 16 + l16][quad * 8];
#pragma unroll
    for (int mt = 0; mt < 4; ++mt)
#pragma unroll
      for (int nt = 0; nt < 4; ++nt)
        acc[mt][nt] = __builtin_amdgcn_mfma_f32_16x16x32_f16(af[mt], bf[nt], acc[mt][nt], 0, 0, 0);
  }
#pragma unroll
  for (int mt = 0; mt < 4; ++mt) {
#pragma unroll
    for (int nt = 0; nt < 4; ++nt) {
#pragma unroll
      for (int rr = 0; rr < 4; ++rr) {
        int grow = rb + wm * 64 + mt * 16 + quad * 4 + rr;
        int gcol = cb + wn * 64 + nt * 16 + l16;
        float vv = acc[mt][nt][rr] + bias[gcol];
        if (mode == 0) {
          ((f16*)out)[(size_t)grow * N + gcol] = (f16)vv;
        } else {
          int b = grow & 63, tt = grow >> 6;
          ((float*)out)[((size_t)b * 512 + tt) * 512 + gcol] = vv;
        }
      }
    }
  }
}

// ---------------- prep: fp16 conversion, transposes, zero-init ----------------
__global__ void prep_kernel(
    const float* __restrict__ x, const float* __restrict__ fc_w,
    const float* __restrict__ w_rz0, const float* __restrict__ b_rz0,
    const float* __restrict__ u_rz0, const float* __restrict__ w_h0,
    const float* __restrict__ b_h0,  const float* __restrict__ u_h0,
    const float* __restrict__ w_rz1, const float* __restrict__ b_rz1,
    const float* __restrict__ u_rz1, const float* __restrict__ w_h1,
    const float* __restrict__ b_h1,  const float* __restrict__ u_h1,
    f16* x16, f16* wcat0, f16* ucat0, f16* wcat1, f16* ucat1, f16* fcw16,
    float* bias0, float* bias1, float* h32_0, float* h32_1, uint32_t* bars)
{
  const int stride = gridDim.x * blockDim.x;
  const int gid = blockIdx.x * blockDim.x + threadIdx.x;
  for (int i = gid; i < 16777216; i += stride) {
    int k = i & 511, b = (i >> 9) & 63, t = i >> 15;
    x16[i] = (f16)x[(((size_t)b << 9) + t) * 512 + k];
  }
  for (int i = gid; i < 786432; i += stride) {
    int n = i >> 9, k = i & 511;
    float a0 = (n < 1024) ? w_rz0[(size_t)n * 512 + k] : w_h0[(size_t)(n - 1024) * 512 + k];
    float c0 = (n < 1024) ? u_rz0[(size_t)n * 512 + k] : u_h0[(size_t)(n - 1024) * 512 + k];
    float a1 = (n < 1024) ? w_rz1[(size_t)n * 512 + k] : w_h1[(size_t)(n - 1024) * 512 + k];
    float c1 = (n < 1024) ? u_rz1[(size_t)n * 512 + k] : u_h1[(size_t)(n - 1024) * 512 + k];
    wcat0[i] = (f16)a0; ucat0[i] = (f16)c0; wcat1[i] = (f16)a1; ucat1[i] = (f16)c1;
  }
  for (int i = gid; i < 262144; i += stride) fcw16[i] = (f16)fc_w[i];
  for (int i = gid; i < 1536; i += stride) {
    bias0[i] = (i < 1024) ? b_rz0[i] : b_h0[i - 1024];
    bias1[i] = (i < 1024) ? b_rz1[i] : b_h1[i - 1024];
  }
  for (int i = gid; i < 32768; i += stride) { h32_0[i] = 0.f; h32_1[i] = 0.f; }
  for (int i = gid; i < 4096; i += stride) bars[i] = 0u;
}

// ---------------- tail: hidden = stack([h0, h1]) ----------------
__global__ void tail_kernel(const float* __restrict__ h32_0,
                            const float* __restrict__ h32_1,
                            float* __restrict__ out)
{
  int i = blockIdx.x * blockDim.x + threadIdx.x;
  if (i < 32768)      out[16777216 + i] = h32_0[i];
  else if (i < 65536) out[16777216 + i] = h32_1[i - 32768];
}

extern "C" void kernel_launch(void* const* d_in, const int* in_sizes, int n_in,
                              void* d_out, int out_size, void* d_ws, size_t ws_size,
                              hipStream_t stream)
{
  const float* x      = (const float*)d_in[0];
  const float* fc_w   = (const float*)d_in[1];
  const float* fc_b   = (const float*)d_in[2];
  const float* l0_w_rz = (const float*)d_in[3];
  const float* l0_b_rz = (const float*)d_in[4];
  const float* l0_u_rz = (const float*)d_in[5];
  const float* l0_w_h  = (const float*)d_in[6];
  const float* l0_b_h  = (const float*)d_in[7];
  const float* l0_u_h  = (const float*)d_in[8];
  const float* l0_g_rz = (const float*)d_in[9];
  const float* l0_be_rz= (const float*)d_in[10];
  const float* l0_g_h  = (const float*)d_in[11];
  const float* l0_be_h = (const float*)d_in[12];
  const float* l1_w_rz = (const float*)d_in[13];
  const float* l1_b_rz = (const float*)d_in[14];
  const float* l1_u_rz = (const float*)d_in[15];
  const float* l1_w_h  = (const float*)d_in[16];
  const float* l1_b_h  = (const float*)d_in[17];
  const float* l1_u_h  = (const float*)d_in[18];
  const float* l1_g_rz = (const float*)d_in[19];
  const float* l1_be_rz= (const float*)d_in[20];
  const float* l1_g_h  = (const float*)d_in[21];
  const float* l1_be_h = (const float*)d_in[22];

  char* ws = (char*)d_ws;
  size_t off = 0;
  auto alloc = [&](size_t bytes) {
    size_t o = off; off += (bytes + 255) & ~(size_t)255; return o;
  };
  f16*   X      = (f16*)  (ws + alloc((size_t)512 * 64 * 1536 * 2)); // X0
  f16*   x16    = (f16*)  (ws + alloc((size_t)512 * 64 * 512 * 2));
  f16*   h_all0 = (f16*)  (ws + alloc((size_t)512 * 64 * 512 * 2));
  f16*   h_all1 = (f16*)  (ws + alloc((size_t)512 * 64 * 512 * 2));
  f16*   wcat0  = (f16*)  (ws + alloc((size_t)1536 * 512 * 2));
  f16*   ucat0  = (f16*)  (ws + alloc((size_t)1536 * 512 * 2));
  f16*   wcat1  = (f16*)  (ws + alloc((size_t)1536 * 512 * 2));
  f16*   ucat1  = (f16*)  (ws + alloc((size_t)1536 * 512 * 2));
  f16*   fcw16  = (f16*)  (ws + alloc((size_t)512 * 512 * 2));
  float* bias0  = (float*)(ws + alloc((size_t)1536 * 4));
  float* bias1  = (float*)(ws + alloc((size_t)1536 * 4));
  float* h32_0  = (float*)(ws + alloc((size_t)64 * 512 * 4));
  float* h32_1  = (float*)(ws + alloc((size_t)64 * 512 * 4));
  float* pre    = (float*)(ws + alloc((size_t)2 * 128 * 2048 * 4));
  uint32_t* bars= (uint32_t*)(ws + alloc((size_t)4096 * 4));

  prep_kernel<<<dim3(2048), dim3(256), 0, stream>>>(
      x, fc_w, l0_w_rz, l0_b_rz, l0_u_rz, l0_w_h, l0_b_h, l0_u_h,
      l1_w_rz, l1_b_rz, l1_u_rz, l1_w_h, l1_b_h, l1_u_h,
      x16, wcat0, ucat0, wcat1, ucat1, fcw16, bias0, bias1,
      h32_0, h32_1, bars);

  // X0 = x @ [w_rz0; w_h0]^T + bias0
  gemm_k512<<<dim3(12, 256), dim3(256), 0, stream>>>(x16, wcat0, bias0, X, 1536, 0);

  // fused, pipelined 2-layer scan
  scan_fused<<<dim3(96), dim3(512), 0, stream>>>(
      X, wcat1, ucat0, ucat1, bias1,
      l0_g_rz, l0_be_rz, l0_g_h, l0_be_h,
      l1_g_rz, l1_be_rz, l1_g_h, l1_be_h,
      h_all0, h_all1, h32_0, h32_1, pre, bars);

  // logits = h1_all @ fc_w^T + fc_b  (B-major into d_out)
  gemm_k512<<<dim3(4, 256), dim3(256), 0, stream>>>(h_all1, fcw16, fc_b, d_out, 512, 1);
  // hidden states
  tail_kernel<<<dim3(256), dim3(256), 0, stream>>>(h32_0, h32_1, (float*)d_out);
}

// Round 7
// 4040.045 us; speedup vs baseline: 3.1247x; 1.5638x over previous
//
#include <hip/hip_runtime.h>
#include <stdint.h>

typedef _Float16 f16;
typedef _Float16 f16x8 __attribute__((ext_vector_type(8)));
typedef float f32x4 __attribute__((ext_vector_type(4)));

#define LN_EPS 1e-5f

// ---- agent-scope (memory-side coherence point) relaxed ops: proven path ----
#define AT_LD(p)   __hip_atomic_load((p), __ATOMIC_RELAXED, __HIP_MEMORY_SCOPE_AGENT)
#define AT_ST(p,v) __hip_atomic_store((p), (v), __ATOMIC_RELAXED, __HIP_MEMORY_SCOPE_AGENT)
#define VM_DRAIN() asm volatile("s_waitcnt vmcnt(0)" ::: "memory")

// ---------------- slot-broadcast chunk barrier (monotonic epochs) -----------
__device__ __forceinline__ void bar_slot(uint32_t* slots, int g, uint32_t e,
                                         int tid) {
  VM_DRAIN();
  __syncthreads();
  if (tid == 0) AT_ST(&slots[g * 16], e);
  if (tid < 12) {
    while (AT_LD(&slots[tid * 16]) < e) __builtin_amdgcn_s_sleep(1);
  }
  __syncthreads();
}

// gates via v_rcp (f16-output precision is far looser than rcp's ~2.5 ulp)
__device__ __forceinline__ float fast_sigmoid(float a) {
  return __builtin_amdgcn_rcpf(1.f + __expf(-a));   // a->-inf: rcp(inf)=0 ok
}
__device__ __forceinline__ float fast_tanh(float a) {
  float x = fminf(fmaxf(a, -15.f), 15.f);
  return 1.f - 2.f * __builtin_amdgcn_rcpf(1.f + __expf(2.f * x));
}

// ---------------- fused 2-layer pipelined scan ----------------
// 96 WGs x 512 threads. chunk = blk&7, g = blk>>3 (0..11).
// chunks 0..3 = layer0 rows 16c, chunks 4..7 = layer1 rows 16(c-4).
// Per step: [L1: poll L0 bar2] -> gather h(t-1) (+L1: h0(t)) from h_all into
// LDS -> phase A MFMA -> pre stores -> bar1 -> X(t+1) prefetch ->
// phase B SPLIT (wave0 of WG g owns row g; wave1 of WGs 0..3 owns row 12+g;
// one row per owner wave, no redundancy) -> owners store h f16 -> bar2.
__global__ __launch_bounds__(512, 2) void scan_fused(
    const f16* __restrict__ X0,      // [512][64][1536] (bias0 folded)
    const f16* __restrict__ W1,      // [1536][512] = [w_rz1; w_h1]
    const f16* __restrict__ U0,      // [1536][512] = [u_rz0; u_h0]
    const f16* __restrict__ U1,      // [1536][512] = [u_rz1; u_h1]
    const float* __restrict__ bias1, // [1536]
    const float* __restrict__ g_rz0, const float* __restrict__ b_rz0,
    const float* __restrict__ g_h0,  const float* __restrict__ b_h0,
    const float* __restrict__ g_rz1, const float* __restrict__ b_rz1,
    const float* __restrict__ g_h1,  const float* __restrict__ b_h1,
    f16* __restrict__ h_all0,        // [512][64][512]
    f16* __restrict__ h_all1,        // [512][64][512]
    float* __restrict__ h32_0, float* __restrict__ h32_1,
    float* __restrict__ pre,         // [2][128][2048] f32
    uint32_t* __restrict__ bars)     // chunk c: bar1 slots @ c*512,
                                     //          bar2 slots @ c*512+256
{
  const int blk   = blockIdx.x;
  const int chunk = blk & 7;
  const int g     = blk >> 3;          // 0..11
  const int layer = chunk >> 2;        // 0 | 1
  const int rows0 = (chunk & 3) * 16;
  const int tid  = threadIdx.x;
  const int wid  = tid >> 6;           // 0..7
  const int lane = tid & 63;
  const int quad = lane >> 4;
  const int l16  = lane & 15;
  const int col  = g * 128 + wid * 16 + l16;   // this lane's output col
  const bool rz_cols = (g * 128 + wid * 16) < 1024;
  // phase-B ownership: one row per owner wave
  const int myrow = (wid == 0) ? g : ((wid == 1 && g < 4) ? 12 + g : -1);

  __shared__ f16 Ash[16][1048];        // [h_own | h1(L1)] tile
  __shared__ float lnrg[1024], lnrb[1024], lnhg[512], lnhb[512];

  {
    const float* srg = layer ? g_rz1 : g_rz0;
    const float* srb = layer ? b_rz1 : b_rz0;
    const float* shg = layer ? g_h1  : g_h0;
    const float* shb = layer ? b_h1  : b_h0;
    for (int i = tid; i < 1024; i += 512) { lnrg[i] = srg[i]; lnrb[i] = srb[i]; }
    if (tid < 512) { lnhg[tid] = shg[tid]; lnhb[tid] = shb[tid]; }
    f16* az = &Ash[0][0];
    for (int i = tid; i < 16 * 1048; i += 512) az[i] = (f16)0.f;
  }

  // resident weight fragments
  f16x8 ufw[16], ufu[16];
  if (layer == 0) {
#pragma unroll
    for (int kk = 0; kk < 16; ++kk)
      ufu[kk] = *(const f16x8*)(U0 + (size_t)col * 512 + kk * 32 + quad * 8);
  } else {
#pragma unroll
    for (int kk = 0; kk < 16; ++kk) {
      ufw[kk] = *(const f16x8*)(W1 + (size_t)col * 512 + kk * 32 + quad * 8);
      ufu[kk] = *(const f16x8*)(U1 + (size_t)col * 512 + kk * 32 + quad * 8);
    }
  }
  const float bval = layer ? bias1[col] : 0.f;

  uint32_t* slots1 = bars + (size_t)chunk * 512;
  uint32_t* slots2 = slots1 + 256;
  uint32_t* peer2  = bars + (size_t)(chunk & 3) * 512 + 256;  // L0 chunk bar2

  float hreg[8];                       // fp32 h master for owned row
#pragma unroll
  for (int i = 0; i < 8; ++i) hreg[i] = 0.f;

  const size_t prerow0 = (size_t)layer * 64 + rows0;
  f16* h_out = layer ? h_all1 : h_all0;

  // ---- X prefetch (L0): phase-A rz part (all waves) + owner-row x_h ----
  float xzc[4] = {0.f, 0.f, 0.f, 0.f};
  f16 xpfc[8];
  if (layer == 0) {
    if (rz_cols) {
      const size_t xb = ((size_t)rows0 + quad * 4) * 1536 + col;
#pragma unroll
      for (int rr = 0; rr < 4; ++rr) xzc[rr] = (float)X0[xb + (size_t)rr * 1536];
    }
    if (myrow >= 0) {
      const size_t xh = ((size_t)rows0 + myrow) * 1536 + 1024 + lane;
#pragma unroll
      for (int i = 0; i < 8; ++i) xpfc[i] = X0[xh + (size_t)i * 64];
    }
  }

  for (int t = 0; t < 512; ++t) {
    // ---- sync-in + gather h into LDS ----
    if (layer == 1) {
      if (tid < 12) {
        while (AT_LD(&peer2[tid * 16]) < (uint32_t)(t + 1))
          __builtin_amdgcn_s_sleep(1);
      }
      __syncthreads();
    }
    {
      const int r  = tid >> 5;
      const int k0 = (tid & 31) * 16;
      if (layer == 1) {
        const uint64_t* s0 =
            (const uint64_t*)(h_all0 + ((size_t)t * 64 + rows0 + r) * 512 + k0);
        uint64_t a0 = AT_LD(s0), a1 = AT_LD(s0 + 1),
                 a2 = AT_LD(s0 + 2), a3 = AT_LD(s0 + 3);
        uint64_t* d0 = (uint64_t*)&Ash[r][k0];
        d0[0] = a0; d0[1] = a1; d0[2] = a2; d0[3] = a3;
        if (t > 0) {
          const uint64_t* s1 =
              (const uint64_t*)(h_all1 + ((size_t)(t - 1) * 64 + rows0 + r) * 512 + k0);
          uint64_t b0 = AT_LD(s1), b1 = AT_LD(s1 + 1),
                   b2 = AT_LD(s1 + 2), b3 = AT_LD(s1 + 3);
          uint64_t* d1 = (uint64_t*)&Ash[r][512 + k0];
          d1[0] = b0; d1[1] = b1; d1[2] = b2; d1[3] = b3;
        }
      } else if (t > 0) {
        const uint64_t* s0 =
            (const uint64_t*)(h_all0 + ((size_t)(t - 1) * 64 + rows0 + r) * 512 + k0);
        uint64_t a0 = AT_LD(s0), a1 = AT_LD(s0 + 1),
                 a2 = AT_LD(s0 + 2), a3 = AT_LD(s0 + 3);
        uint64_t* d0 = (uint64_t*)&Ash[r][k0];
        d0[0] = a0; d0[1] = a1; d0[2] = a2; d0[3] = a3;
      }
    }
    __syncthreads();

    // ---- phase A ----
    f32x4 accw = (f32x4){0.f, 0.f, 0.f, 0.f};
    f32x4 accu = (f32x4){0.f, 0.f, 0.f, 0.f};
    if (layer == 0) {
#pragma unroll
      for (int kk = 0; kk < 8; ++kk) {
        f16x8 af = *(const f16x8*)&Ash[l16][kk * 32 + quad * 8];
        accw = __builtin_amdgcn_mfma_f32_16x16x32_f16(af, ufu[kk], accw, 0, 0, 0);
      }
#pragma unroll
      for (int kk = 8; kk < 16; ++kk) {
        f16x8 af = *(const f16x8*)&Ash[l16][kk * 32 + quad * 8];
        accu = __builtin_amdgcn_mfma_f32_16x16x32_f16(af, ufu[kk], accu, 0, 0, 0);
      }
    } else {
      accw = (f32x4){bval, bval, bval, bval};
#pragma unroll
      for (int kk = 0; kk < 16; ++kk) {
        f16x8 af = *(const f16x8*)&Ash[l16][kk * 32 + quad * 8];
        accw = __builtin_amdgcn_mfma_f32_16x16x32_f16(af, ufw[kk], accw, 0, 0, 0);
      }
#pragma unroll
      for (int kk = 0; kk < 16; ++kk) {
        f16x8 af = *(const f16x8*)&Ash[l16][512 + kk * 32 + quad * 8];
        accu = __builtin_amdgcn_mfma_f32_16x16x32_f16(af, ufu[kk], accu, 0, 0, 0);
      }
    }

    // ---- pre stores (double-buffered) ----
    const int buf = t & 1;
    {
      float* prow0 = pre + ((size_t)buf * 128 + prerow0 + quad * 4) * 2048;
      if (layer == 0) {
#pragma unroll
        for (int rr = 0; rr < 4; ++rr)
          AT_ST(&prow0[(size_t)rr * 2048 + col], accw[rr] + accu[rr] + xzc[rr]);
      } else if (rz_cols) {
#pragma unroll
        for (int rr = 0; rr < 4; ++rr)
          AT_ST(&prow0[(size_t)rr * 2048 + col], accw[rr] + accu[rr]);
      } else {
#pragma unroll
        for (int rr = 0; rr < 4; ++rr) {
          AT_ST(&prow0[(size_t)rr * 2048 + col],       accu[rr]);  // u_h part
          AT_ST(&prow0[(size_t)rr * 2048 + col + 512], accw[rr]);  // x_h (+bias)
        }
      }
    }

    bar_slot(slots1, g, (uint32_t)(t + 1), tid);

    // ---- X(t+1) prefetch (L0): hides under phase B ----
    float xzn[4] = {0.f, 0.f, 0.f, 0.f};
    f16 xpfn[8];
    if (layer == 0) {
      const int tn = (t < 511) ? t + 1 : 511;
      if (rz_cols) {
        const size_t xb = ((size_t)tn * 64 + rows0 + quad * 4) * 1536 + col;
#pragma unroll
        for (int rr = 0; rr < 4; ++rr) xzn[rr] = (float)X0[xb + (size_t)rr * 1536];
      }
      if (myrow >= 0) {
        const size_t xh = ((size_t)tn * 64 + rows0 + myrow) * 1536 + 1024 + lane;
#pragma unroll
        for (int i = 0; i < 8; ++i) xpfn[i] = X0[xh + (size_t)i * 64];
      }
    }

    // ---- phase B: one row per owner wave (no redundancy) ----
    if (myrow >= 0) {
      const int brow = rows0 + myrow;
      float* prow =
          pre + ((size_t)buf * 128 + (size_t)layer * 64 + brow) * 2048;
      float v[16], hu[8], xh[8];
#pragma unroll
      for (int i = 0; i < 16; ++i) v[i] = AT_LD(&prow[i * 64 + lane]);
#pragma unroll
      for (int i = 0; i < 8; ++i)  hu[i] = AT_LD(&prow[1024 + i * 64 + lane]);
      if (layer) {
#pragma unroll
        for (int i = 0; i < 8; ++i) xh[i] = AT_LD(&prow[1536 + i * 64 + lane]);
      }
      float s1 = 0.f, s2 = 0.f;
#pragma unroll
      for (int i = 0; i < 16; ++i) { s1 += v[i]; s2 += v[i] * v[i]; }
#pragma unroll
      for (int off = 1; off < 64; off <<= 1) {
        s1 += __shfl_xor(s1, off); s2 += __shfl_xor(s2, off);
      }
      float m    = s1 * (1.f / 1024.f);
      float var  = s2 * (1.f / 1024.f) - m * m;
      float rstd = rsqrtf(var + LN_EPS);
      float rg[8], zg[8];
#pragma unroll
      for (int i = 0; i < 16; ++i) {
        int n = i * 64 + lane;
        float a = (v[i] - m) * rstd * lnrg[n] + lnrb[n];
        float s = fast_sigmoid(a);
        if (i < 8) rg[i] = s; else zg[i - 8] = s;
      }
      float ht[8];
      float u1 = 0.f, u2 = 0.f;
#pragma unroll
      for (int i = 0; i < 8; ++i) {
        float xv = layer ? xh[i] : (float)xpfc[i];
        float hv = xv + rg[i] * hu[i];
        ht[i] = hv; u1 += hv; u2 += hv * hv;
      }
#pragma unroll
      for (int off = 1; off < 64; off <<= 1) {
        u1 += __shfl_xor(u1, off); u2 += __shfl_xor(u2, off);
      }
      float m2    = u1 * (1.f / 512.f);
      float var2  = u2 * (1.f / 512.f) - m2 * m2;
      float rstd2 = rsqrtf(var2 + LN_EPS);
#pragma unroll
      for (int i = 0; i < 8; ++i) {
        int n = i * 64 + lane;
        float a  = (ht[i] - m2) * rstd2 * lnhg[n] + lnhb[n];
        float th = fast_tanh(a);
        float hn = (1.f - zg[i]) * hreg[i] + zg[i] * th;
        hreg[i] = hn;
        union { f16 h; uint16_t u; } cv; cv.h = (f16)hn;
        AT_ST((uint16_t*)&h_out[((size_t)t * 64 + brow) * 512 + n], cv.u);
      }
    }

    bar_slot(slots2, g, (uint32_t)(t + 1), tid);

    // roll X prefetch registers
    if (layer == 0) {
#pragma unroll
      for (int rr = 0; rr < 4; ++rr) xzc[rr] = xzn[rr];
#pragma unroll
      for (int i = 0; i < 8; ++i) xpfc[i] = xpfn[i];
    }
  }

  if (myrow >= 0) {
    float* hdst = layer ? h32_1 : h32_0;
    const int brow = rows0 + myrow;
#pragma unroll
    for (int i = 0; i < 8; ++i)
      hdst[(size_t)brow * 512 + i * 64 + lane] = hreg[i];
  }
}

// ---------------- generic K=512 fp16 GEMM: C = A @ W^T + bias ----------------
__global__ void gemm_k512(const f16* __restrict__ A, const f16* __restrict__ W,
                          const float* __restrict__ bias, void* __restrict__ out,
                          int N, int mode)
{
  __shared__ f16 As[128][56];
  __shared__ f16 Bs[128][56];
  const int tid = threadIdx.x;
  const int wid = tid >> 6, lane = tid & 63, quad = lane >> 4, l16 = lane & 15;
  const int wm = wid & 1, wn = wid >> 1;
  const int rb = blockIdx.y * 128, cb = blockIdx.x * 128;
  f32x4 acc[4][4];
#pragma unroll
  for (int i = 0; i < 4; ++i)
#pragma unroll
    for (int j = 0; j < 4; ++j) acc[i][j] = (f32x4){0.f, 0.f, 0.f, 0.f};
  const int srow = tid >> 1;
  const int skh  = (tid & 1) * 16;
  for (int kk = 0; kk < 16; ++kk) {
    __syncthreads();
    {
      const f16* a = A + (size_t)(rb + srow) * 512 + kk * 32 + skh;
      *(f16x8*)&As[srow][skh]     = *(const f16x8*)(a);
      *(f16x8*)&As[srow][skh + 8] = *(const f16x8*)(a + 8);
      const f16* b = W + (size_t)(cb + srow) * 512 + kk * 32 + skh;
      *(f16x8*)&Bs[srow][skh]     = *(const f16x8*)(b);
      *(f16x8*)&Bs[srow][skh + 8] = *(const f16x8*)(b + 8);
    }
    __syncthreads();
    f16x8 af[4], bf[4];
#pragma unroll
    for (int mt = 0; mt < 4; ++mt) af[mt] = *(const f16x8*)&As[wm * 64 + mt * 16 + l16][quad * 8];
#pragma unroll
    for (int nt = 0; nt < 4; ++nt) bf[nt] = *(const f16x8*)&Bs[wn * 64 + nt * 16 + l16][quad * 8];
#pragma unroll
    for (int mt = 0; mt < 4; ++mt)
#pragma unroll
      for (int nt = 0; nt < 4; ++nt)
        acc[mt][nt] = __builtin_amdgcn_mfma_f32_16x16x32_f16(af[mt], bf[nt], acc[mt][nt], 0, 0, 0);
  }
#pragma unroll
  for (int mt = 0; mt < 4; ++mt) {
#pragma unroll
    for (int nt = 0; nt < 4; ++nt) {
#pragma unroll
      for (int rr = 0; rr < 4; ++rr) {
        int grow = rb + wm * 64 + mt * 16 + quad * 4 + rr;
        int gcol = cb + wn * 64 + nt * 16 + l16;
        float vv = acc[mt][nt][rr] + bias[gcol];
        if (mode == 0) {
          ((f16*)out)[(size_t)grow * N + gcol] = (f16)vv;
        } else {
          int b = grow & 63, tt = grow >> 6;
          ((float*)out)[((size_t)b * 512 + tt) * 512 + gcol] = vv;
        }
      }
    }
  }
}

// ---------------- prep: fp16 conversion, transposes, zero-init ----------------
__global__ void prep_kernel(
    const float* __restrict__ x, const float* __restrict__ fc_w,
    const float* __restrict__ w_rz0, const float* __restrict__ b_rz0,
    const float* __restrict__ u_rz0, const float* __restrict__ w_h0,
    const float* __restrict__ b_h0,  const float* __restrict__ u_h0,
    const float* __restrict__ w_rz1, const float* __restrict__ b_rz1,
    const float* __restrict__ u_rz1, const float* __restrict__ w_h1,
    const float* __restrict__ b_h1,  const float* __restrict__ u_h1,
    f16* x16, f16* wcat0, f16* ucat0, f16* wcat1, f16* ucat1, f16* fcw16,
    float* bias0, float* bias1, float* h32_0, float* h32_1, uint32_t* bars)
{
  const int stride = gridDim.x * blockDim.x;
  const int gid = blockIdx.x * blockDim.x + threadIdx.x;
  for (int i = gid; i < 16777216; i += stride) {
    int k = i & 511, b = (i >> 9) & 63, t = i >> 15;
    x16[i] = (f16)x[(((size_t)b << 9) + t) * 512 + k];
  }
  for (int i = gid; i < 786432; i += stride) {
    int n = i >> 9, k = i & 511;
    float a0 = (n < 1024) ? w_rz0[(size_t)n * 512 + k] : w_h0[(size_t)(n - 1024) * 512 + k];
    float c0 = (n < 1024) ? u_rz0[(size_t)n * 512 + k] : u_h0[(size_t)(n - 1024) * 512 + k];
    float a1 = (n < 1024) ? w_rz1[(size_t)n * 512 + k] : w_h1[(size_t)(n - 1024) * 512 + k];
    float c1 = (n < 1024) ? u_rz1[(size_t)n * 512 + k] : u_h1[(size_t)(n - 1024) * 512 + k];
    wcat0[i] = (f16)a0; ucat0[i] = (f16)c0; wcat1[i] = (f16)a1; ucat1[i] = (f16)c1;
  }
  for (int i = gid; i < 262144; i += stride) fcw16[i] = (f16)fc_w[i];
  for (int i = gid; i < 1536; i += stride) {
    bias0[i] = (i < 1024) ? b_rz0[i] : b_h0[i - 1024];
    bias1[i] = (i < 1024) ? b_rz1[i] : b_h1[i - 1024];
  }
  for (int i = gid; i < 32768; i += stride) { h32_0[i] = 0.f; h32_1[i] = 0.f; }
  for (int i = gid; i < 4096; i += stride) bars[i] = 0u;
}

// ---------------- tail: hidden = stack([h0, h1]) ----------------
__global__ void tail_kernel(const float* __restrict__ h32_0,
                            const float* __restrict__ h32_1,
                            float* __restrict__ out)
{
  int i = blockIdx.x * blockDim.x + threadIdx.x;
  if (i < 32768)      out[16777216 + i] = h32_0[i];
  else if (i < 65536) out[16777216 + i] = h32_1[i - 32768];
}

extern "C" void kernel_launch(void* const* d_in, const int* in_sizes, int n_in,
                              void* d_out, int out_size, void* d_ws, size_t ws_size,
                              hipStream_t stream)
{
  const float* x      = (const float*)d_in[0];
  const float* fc_w   = (const float*)d_in[1];
  const float* fc_b   = (const float*)d_in[2];
  const float* l0_w_rz = (const float*)d_in[3];
  const float* l0_b_rz = (const float*)d_in[4];
  const float* l0_u_rz = (const float*)d_in[5];
  const float* l0_w_h  = (const float*)d_in[6];
  const float* l0_b_h  = (const float*)d_in[7];
  const float* l0_u_h  = (const float*)d_in[8];
  const float* l0_g_rz = (const float*)d_in[9];
  const float* l0_be_rz= (const float*)d_in[10];
  const float* l0_g_h  = (const float*)d_in[11];
  const float* l0_be_h = (const float*)d_in[12];
  const float* l1_w_rz = (const float*)d_in[13];
  const float* l1_b_rz = (const float*)d_in[14];
  const float* l1_u_rz = (const float*)d_in[15];
  const float* l1_w_h  = (const float*)d_in[16];
  const float* l1_b_h  = (const float*)d_in[17];
  const float* l1_u_h  = (const float*)d_in[18];
  const float* l1_g_rz = (const float*)d_in[19];
  const float* l1_be_rz= (const float*)d_in[20];
  const float* l1_g_h  = (const float*)d_in[21];
  const float* l1_be_h = (const float*)d_in[22];

  char* ws = (char*)d_ws;
  size_t off = 0;
  auto alloc = [&](size_t bytes) {
    size_t o = off; off += (bytes + 255) & ~(size_t)255; return o;
  };
  f16*   X      = (f16*)  (ws + alloc((size_t)512 * 64 * 1536 * 2)); // X0
  f16*   x16    = (f16*)  (ws + alloc((size_t)512 * 64 * 512 * 2));
  f16*   h_all0 = (f16*)  (ws + alloc((size_t)512 * 64 * 512 * 2));
  f16*   h_all1 = (f16*)  (ws + alloc((size_t)512 * 64 * 512 * 2));
  f16*   wcat0  = (f16*)  (ws + alloc((size_t)1536 * 512 * 2));
  f16*   ucat0  = (f16*)  (ws + alloc((size_t)1536 * 512 * 2));
  f16*   wcat1  = (f16*)  (ws + alloc((size_t)1536 * 512 * 2));
  f16*   ucat1  = (f16*)  (ws + alloc((size_t)1536 * 512 * 2));
  f16*   fcw16  = (f16*)  (ws + alloc((size_t)512 * 512 * 2));
  float* bias0  = (float*)(ws + alloc((size_t)1536 * 4));
  float* bias1  = (float*)(ws + alloc((size_t)1536 * 4));
  float* h32_0  = (float*)(ws + alloc((size_t)64 * 512 * 4));
  float* h32_1  = (float*)(ws + alloc((size_t)64 * 512 * 4));
  float* pre    = (float*)(ws + alloc((size_t)2 * 128 * 2048 * 4));
  uint32_t* bars= (uint32_t*)(ws + alloc((size_t)4096 * 4));

  prep_kernel<<<dim3(2048), dim3(256), 0, stream>>>(
      x, fc_w, l0_w_rz, l0_b_rz, l0_u_rz, l0_w_h, l0_b_h, l0_u_h,
      l1_w_rz, l1_b_rz, l1_u_rz, l1_w_h, l1_b_h, l1_u_h,
      x16, wcat0, ucat0, wcat1, ucat1, fcw16, bias0, bias1,
      h32_0, h32_1, bars);

  // X0 = x @ [w_rz0; w_h0]^T + bias0
  gemm_k512<<<dim3(12, 256), dim3(256), 0, stream>>>(x16, wcat0, bias0, X, 1536, 0);

  // fused, pipelined 2-layer scan
  scan_fused<<<dim3(96), dim3(512), 0, stream>>>(
      X, wcat1, ucat0, ucat1, bias1,
      l0_g_rz, l0_be_rz, l0_g_h, l0_be_h,
      l1_g_rz, l1_be_rz, l1_g_h, l1_be_h,
      h_all0, h_all1, h32_0, h32_1, pre, bars);

  // logits = h1_all @ fc_w^T + fc_b  (B-major into d_out)
  gemm_k512<<<dim3(4, 256), dim3(256), 0, stream>>>(h_all1, fcw16, fc_b, d_out, 512, 1);
  // hidden states
  tail_kernel<<<dim3(256), dim3(256), 0, stream>>>(h32_0, h32_1, (float*)d_out);
}